// Round 18
// baseline (167.355 us; speedup 1.0000x reference)
//
#include <hip/hip_runtime.h>
#include <math.h>

#define S_LEN    16
#define NTOK     64     // tokens, m = s*4 + b
#define DMODEL   512
#define XB_COLS  2176   // x part (2048) + B part (128); z and C parts are dead code
#define ZX_COLS  2240   // XB_COLS + 64 dt columns
#define NCLASS   2513
#define FEATDIM  4096
#define PD_STRIDE 2516  // padded class stride
#define APAD     68     // padded LDS row for phase D

typedef float f4v __attribute__((ext_vector_type(4)));

// ---- software grid barrier (all 256 blocks co-resident: 48KB LDS -> >=2/CU) ----
__device__ __forceinline__ void gsync(unsigned* bar, int idx) {
    __syncthreads();
    if (threadIdx.x == 0) {
        __threadfence();                       // release: prior writes visible
        atomicAdd(&bar[idx], 1u);
        while (atomicAdd(&bar[idx], 0u) < 256u)
            __builtin_amdgcn_s_sleep(8);
        __threadfence();                       // acquire: see other blocks' writes
    }
    __syncthreads();
}

// ---------- Phase A: in_proj partials (old k_fpart) ----------
__device__ __forceinline__ void phaseA(float* lds, int unit, int tid,
                                       const float* __restrict__ X,
                                       const float* __restrict__ W,
                                       float* __restrict__ partF) {
    const int kf = unit / 35;
    const int jb = (unit % 35) * 64;
    const int k0 = kf * 64;
    float (*A)[64] = (float(*)[64])lds;
    float (*B)[64] = (float(*)[64])(lds + 4096);

    __syncthreads();
    {
        const int t  = tid >> 2;
        const int kq = tid & 3;
        const int xrow = (t & 3) * 16 + (t >> 2);
        const int e = (jb + t < XB_COLS) ? (2048 + jb + t) : (2176 + jb + t);
#pragma unroll
        for (int q = 0; q < 4; ++q) {
            const int kk = kq * 16 + q * 4;
            const float4 va = *reinterpret_cast<const float4*>(
                X + (size_t)xrow * DMODEL + k0 + kk);
            A[kk + 0][t] = va.x; A[kk + 1][t] = va.y;
            A[kk + 2][t] = va.z; A[kk + 3][t] = va.w;
            const float4 vb = *reinterpret_cast<const float4*>(
                W + (size_t)e * DMODEL + k0 + kk);
            B[kk + 0][t] = vb.x; B[kk + 1][t] = vb.y;
            B[kk + 2][t] = vb.z; B[kk + 3][t] = vb.w;
        }
    }
    __syncthreads();

    const int ti = tid >> 4;
    const int ci = tid & 15;
    float acc[4][4] = {{0.f}};
#pragma unroll 4
    for (int k = 0; k < 64; ++k) {
        const f4v a = *reinterpret_cast<const f4v*>(&A[k][ti * 4]);
        const f4v b = *reinterpret_cast<const f4v*>(&B[k][ci * 4]);
#pragma unroll
        for (int j = 0; j < 4; ++j)
#pragma unroll
            for (int l = 0; l < 4; ++l)
                acc[j][l] += a[j] * b[l];
    }
#pragma unroll
    for (int jj = 0; jj < 4; ++jj) {
        f4v s; s[0] = acc[jj][0]; s[1] = acc[jj][1];
               s[2] = acc[jj][2]; s[3] = acc[jj][3];
        *reinterpret_cast<f4v*>(
            partF + ((size_t)kf * NTOK + ti * 4 + jj) * ZX_COLS + jb + ci * 4) = s;
    }
}

// ---------- Phase B: reduce partials + conv/silu + dt/dA (old k_fepi) -------------
__device__ __forceinline__ void phaseB(int unit, int tid,
                                       const float* __restrict__ partF, int KF,
                                       const float* __restrict__ conv_w,
                                       const float* __restrict__ conv_b,
                                       const float* __restrict__ dt_bias,
                                       const float* __restrict__ A_log,
                                       float* __restrict__ u,
                                       float* __restrict__ aArr,
                                       float* __restrict__ dArr) {
    const int idx4 = unit * 256 + tid;
    const int m  = idx4 / 560;
    const int j  = (idx4 - m * 560) * 4;

    f4v acc = {0.f, 0.f, 0.f, 0.f};
    for (int kf = 0; kf < KF; ++kf)
        acc += *reinterpret_cast<const f4v*>(
            partF + ((size_t)kf * NTOK + m) * ZX_COLS + j);

    if (j < XB_COLS) {
        float wk[4][4], cb[4];
#pragma unroll
        for (int e = 0; e < 4; ++e) {
            const float4 cwv = *reinterpret_cast<const float4*>(conv_w + (j + e) * 4);
            cb[e] = conv_b[j + e];
            wk[e][0] = cwv.w;
            wk[e][1] = wk[e][0] + cwv.z;
            wk[e][2] = wk[e][1] + cwv.y;
            wk[e][3] = wk[e][2] + cwv.x;
        }
#pragma unroll
        for (int k = 0; k < 4; ++k) {
            f4v o;
#pragma unroll
            for (int e = 0; e < 4; ++e) {
                const float v = acc[e] * wk[e][k] + cb[e];
                o[e] = v / (1.f + expf(-v));
            }
            *reinterpret_cast<f4v*>(u + ((size_t)k * NTOK + m) * XB_COLS + j) = o;
        }
    } else {
        const int h = j - XB_COLS;
        f4v dv, av;
#pragma unroll
        for (int e = 0; e < 4; ++e) {
            const float x = acc[e] + dt_bias[h + e];
            const float d = (x > 20.f) ? x : log1pf(expf(x));
            dv[e] = d;
            av[e] = expf(-d * expf(A_log[h + e]));
        }
        *reinterpret_cast<f4v*>(dArr + m * 64 + h) = dv;
        *reinterpret_cast<f4v*>(aArr + m * 64 + h) = av;
    }
}

// ---------- Phase C: collapsed SSM -> feats (old k_feats, i-split x4) -------------
__device__ __forceinline__ void phaseC(float* lds, int bx, int tid,
                                       const float* __restrict__ u,
                                       const float* __restrict__ aArr,
                                       const float* __restrict__ dArr,
                                       float* __restrict__ feats) {
    const int g  = bx & 3;
    const int tb = bx >> 2;
    const int t  = tb >> 2;
    const int b  = tb & 3;
    const int K = 16 - t;
    const int nvec = t + 5;

    float (*q)[64]   = (float(*)[64])lds;
    float (*cu)[64]  = (float(*)[64])(lds + 1024);
    float (*WV)[8]   = (float(*)[8])(lds + 1280);
    float (*Bv)[128] = (float(*)[128])(lds + 1440);

    __syncthreads();
    if (tid < 64) {
        const int h = tid;
        const int mt = t * 4 + b;
        const float a   = aArr[mt * 64 + h];
        const float dtv = dArr[mt * 64 + h];
        float p = 1.f;
        float c3 = 0.f, c2 = 0.f, c1 = 0.f, c0 = 0.f, cs = 0.f;
        for (int j = 0; j <= K + 1; ++j) {
            if (j <= K - 3) c3 += p;
            if (j == K - 2) c2 = p;
            if (j == K - 1) c1 = p;
            if (j == K)     c0 = p;
            if (j == K + 1) cs = p;
            p *= a;
        }
        cu[0][h] = dtv * c0;
        cu[1][h] = dtv * c1;
        cu[2][h] = dtv * c2;
        cu[3][h] = dtv * c3;
        float prod = 1.f;
        for (int s = t; s >= 0; --s) {
            const int ms = s * 4 + b;
            q[s][h] = cs * prod * dArr[ms * 64 + h];
            prod *= aArr[ms * 64 + h];
        }
    }
    __syncthreads();

    {
        const int il = tid & 7;
        const int i  = g * 8 + il;
        const int vs = tid >> 3;
        for (int v = vs; v < nvec; v += 32) {
            float acc = 0.f;
            if (v <= t) {
                const float* base = u + (size_t)(v * 4 + b) * XB_COLS;
                for (int h = 0; h < 64; ++h) acc += q[v][h] * base[h * 32 + i];
            } else {
                const int kk = v - t - 1;
                const float* base = u + ((size_t)kk * NTOK + t * 4 + b) * XB_COLS;
                for (int h = 0; h < 64; ++h) acc += cu[kk][h] * base[h * 32 + i];
            }
            WV[v][il] = acc;
        }
    }
    for (int x = tid; x < nvec * 128; x += 256) {
        const int v = x >> 7, n = x & 127;
        size_t src;
        if (v <= t) src = (size_t)(v * 4 + b) * XB_COLS + 2048 + n;
        else        src = ((size_t)(v - t - 1) * NTOK + t * 4 + b) * XB_COLS + 2048 + n;
        Bv[v][n] = u[src];
    }
    __syncthreads();

    {
        const int il = tid >> 5;
        const int i  = g * 8 + il;
        const int n0 = (tid & 31) * 4;
        const int r  = b * 16 + t;
        float acc[4] = {0.f, 0.f, 0.f, 0.f};
        for (int v = 0; v < nvec; ++v) {
            const float wvv = WV[v][il];
#pragma unroll
            for (int nn = 0; nn < 4; ++nn) acc[nn] += wvv * Bv[v][n0 + nn];
        }
        f4v o;
#pragma unroll
        for (int nn = 0; nn < 4; ++nn) o[nn] = acc[nn] * (1.f / 64.f);
        *reinterpret_cast<f4v*>(feats + (size_t)r * FEATDIM + i * 128 + n0) = o;
    }
    __syncthreads();
}

// ---------- Phase D: classifier GEMM tile (old k_cls) -----------------------------
__device__ __forceinline__ void phaseD(float* lds, int unit, int tid, int KC,
                                       const float* __restrict__ feats,
                                       const float* __restrict__ Wc,
                                       float* __restrict__ partialD) {
    const int lane  = tid & 63;
    const int wv    = tid >> 6;
    const int ks    = unit / 40;
    const int cls0  = (unit % 40) * 64;
    const int chunk = FEATDIM / KC;
    const int nsub  = chunk / 64;

    float* A = lds;                              // [k][APAD]
    float* B = lds + 64 * APAD;

    const int rq = tid >> 4;
    const int kq = tid & 15;
    int crow[4];
#pragma unroll
    for (int r = 0; r < 4; ++r) {
        int cr = cls0 + rq * 4 + r; if (cr > NCLASS - 1) cr = NCLASS - 1;
        crow[r] = cr;
    }

    const int ti = lane >> 3;
    const int ci = lane & 7;

    float4 pa[4], pb[4];
#define LOADREGS(ST)                                                      \
    do {                                                                  \
        const int k0_ = ks * chunk + (ST) * 64 + kq * 4;                  \
        _Pragma("unroll")                                                 \
        for (int r = 0; r < 4; ++r) {                                     \
            pa[r] = *reinterpret_cast<const float4*>(                     \
                feats + (size_t)(rq * 4 + r) * FEATDIM + k0_);            \
            pb[r] = *reinterpret_cast<const float4*>(                     \
                Wc + (size_t)crow[r] * FEATDIM + k0_);                    \
        }                                                                 \
    } while (0)

    float acc[8][8] = {{0.f}};

    LOADREGS(0);
    for (int st = 0; st < nsub; ++st) {
        __syncthreads();
        {
#pragma unroll
            for (int s = 0; s < 4; ++s) {
                const int kk = kq * 4 + s;
                f4v wa; wa[0] = (&pa[0].x)[s]; wa[1] = (&pa[1].x)[s];
                        wa[2] = (&pa[2].x)[s]; wa[3] = (&pa[3].x)[s];
                *reinterpret_cast<f4v*>(&A[kk * APAD + rq * 4]) = wa;
                f4v wb; wb[0] = (&pb[0].x)[s]; wb[1] = (&pb[1].x)[s];
                        wb[2] = (&pb[2].x)[s]; wb[3] = (&pb[3].x)[s];
                *reinterpret_cast<f4v*>(&B[kk * APAD + rq * 4]) = wb;
            }
        }
        if (st + 1 < nsub) LOADREGS(st + 1);
        __syncthreads();

#pragma unroll
        for (int k = 0; k < 16; ++k) {
            const int kk = wv * 16 + k;
            const f4v a0 = *reinterpret_cast<const f4v*>(&A[kk * APAD + ti * 4]);
            const f4v a1 = *reinterpret_cast<const f4v*>(&A[kk * APAD + 32 + ti * 4]);
            const f4v b0 = *reinterpret_cast<const f4v*>(&B[kk * APAD + ci * 4]);
            const f4v b1 = *reinterpret_cast<const f4v*>(&B[kk * APAD + 32 + ci * 4]);
#pragma unroll
            for (int j = 0; j < 4; ++j) {
#pragma unroll
                for (int l = 0; l < 4; ++l) {
                    acc[j][l]         += a0[j] * b0[l];
                    acc[j][l + 4]     += a0[j] * b1[l];
                    acc[j + 4][l]     += a1[j] * b0[l];
                    acc[j + 4][l + 4] += a1[j] * b1[l];
                }
            }
        }
    }
#undef LOADREGS

    const size_t obase = (size_t)ks * (NTOK * PD_STRIDE);
#pragma unroll
    for (int half = 0; half < 2; ++half) {
        __syncthreads();
#pragma unroll
        for (int i = 0; i < 32; ++i)
            lds[wv * 2048 + i * 64 + lane] = acc[half * 4 + (i >> 3)][i & 7];
        __syncthreads();

        float s[8];
#pragma unroll
        for (int l = 0; l < 8; ++l)
            s[l] = lds[       (wv * 8 + l) * 64 + lane]
                 + lds[2048 + (wv * 8 + l) * 64 + lane]
                 + lds[4096 + (wv * 8 + l) * 64 + lane]
                 + lds[6144 + (wv * 8 + l) * 64 + lane];

        const int row = half * 32 + ti * 4 + wv;
#pragma unroll
        for (int cb = 0; cb < 2; ++cb) {
            const int c = cls0 + cb * 32 + ci * 4;
            f4v v4;
#pragma unroll
            for (int l = 0; l < 4; ++l) v4[l] = s[cb * 4 + l];
            float* dst = partialD + obase + (size_t)row * PD_STRIDE + c;
            if (c + 3 < NCLASS) {
                *reinterpret_cast<f4v*>(dst) = v4;
            } else {
#pragma unroll
                for (int l = 0; l < 4; ++l)
                    if (c + l < NCLASS) dst[l] = v4[l];
            }
        }
    }
    __syncthreads();
}

// ---------- Phase E: reduce split-K partials + bias -> out ------------------------
__device__ __forceinline__ void phaseE(int unit, int tid, int NP,
                                       const float* __restrict__ partialD,
                                       const float* __restrict__ cls_b,
                                       float* __restrict__ out) {
    const int r = unit / 10;
    const int c = (unit % 10) * 256 + tid;
    if (c >= NCLASS) return;
    float s = cls_b[c];
    for (int p = 0; p < NP; ++p)
        s += partialD[(size_t)p * (NTOK * PD_STRIDE) + (size_t)r * PD_STRIDE + c];
    out[(size_t)r * NCLASS + c] = s;
}

// ---------- Mega kernel: all phases, software grid barrier between ----------------
__global__ __launch_bounds__(256) void k_mega(const float* __restrict__ X,
                                              const float* __restrict__ W,
                                              const float* __restrict__ conv_w,
                                              const float* __restrict__ conv_b,
                                              const float* __restrict__ dt_bias,
                                              const float* __restrict__ A_log,
                                              const float* __restrict__ Wc,
                                              const float* __restrict__ cls_b,
                                              float* __restrict__ partF,
                                              float* __restrict__ u,
                                              float* __restrict__ aArr,
                                              float* __restrict__ dArr,
                                              float* __restrict__ feats,
                                              float* __restrict__ partialD,
                                              float* __restrict__ out,
                                              unsigned* __restrict__ bar,
                                              int KC) {
    __shared__ float lds[12288];                // 48KB pool, re-cast per phase
    const int bid = blockIdx.x;
    const int tid = threadIdx.x;

    for (int unit = bid; unit < 280; unit += 256)
        phaseA(lds, unit, tid, X, W, partF);
    gsync(bar, 0);

    for (int unit = bid; unit < 140; unit += 256)
        phaseB(unit, tid, partF, 8, conv_w, conv_b, dt_bias, A_log, u, aArr, dArr);
    gsync(bar, 1);

    phaseC(lds, bid, tid, u, aArr, dArr, feats);   // exactly 256 units
    gsync(bar, 2);

    for (int unit = bid; unit < 40 * KC; unit += 256)
        phaseD(lds, unit, tid, KC, feats, Wc, partialD);
    gsync(bar, 3);

    for (int unit = bid; unit < 640; unit += 256)
        phaseE(unit, tid, KC, partialD, cls_b, out);
}

// ------------------------------------------------------------------------------
extern "C" void kernel_launch(void* const* d_in, const int* in_sizes, int n_in,
                              void* d_out, int out_size, void* d_ws, size_t ws_size,
                              hipStream_t stream) {
    const float* inputs  = (const float*)d_in[0];
    const float* in_proj = (const float*)d_in[1];
    const float* conv_w  = (const float*)d_in[2];
    const float* conv_b  = (const float*)d_in[3];
    const float* dt_bias = (const float*)d_in[4];
    const float* A_log   = (const float*)d_in[5];
    const float* cls_w   = (const float*)d_in[6];
    const float* cls_b   = (const float*)d_in[7];
    float* out = (float*)d_out;

    float* ws = (float*)d_ws;
    float* aArr    = ws;               //   4096
    float* dArr    = ws + 4096;        //   4096
    float* feats   = ws + 8192;        // 262144 (row-major [r][4096])
    float* scr     = ws + 270336;
    float* u       = scr;              // 557056 (dead after phase C)
    float* partF   = scr + 557056;     // 8*64*2240 (dead after phase B)
    float* partialD = scr;             // KC*64*2516 (written in phase D)

    // tiers: bytes = (270336 + max(1703936, KC*64*2516)) * 4  + 16B barrier
    //   KC=16 -> 11,386,880 + 16     KC=8 -> 7,897,088 + 16
    int KC;
    size_t barOff;                     // float offset of barrier region
    if (ws_size >= 11386944u) { KC = 16; barOff = 270336 + 2576384; }
    else                      { KC = 8;  barOff = 270336 + 1703936; }
    unsigned* bar = (unsigned*)(ws + barOff);

    hipMemsetAsync(bar, 0, 4 * sizeof(unsigned), stream);
    k_mega<<<256, 256, 0, stream>>>(inputs, in_proj, conv_w, conv_b,
                                    dt_bias, A_log, cls_w, cls_b,
                                    partF, u, aArr, dArr, feats, partialD,
                                    out, bar, KC);
}